// Round 4
// baseline (235.400 us; speedup 1.0000x reference)
//
#include <hip/hip_runtime.h>

// YOLO v1 loss, forward only — fused single-kernel version.
// predictions/target: (N, 7, 7, 30) f32, D = 2*5 + 20. Output: scalar f32.
//
// R3 post-mortem: stage1 runs at ~5.85 TB/s effective (>=93% of the 6.29 TB/s
// streaming ceiling); reg-staged vs DMA-staged identical -> memory-system
// bound. Remaining cost is the 2nd dispatch + launch gap (~3-5us). This round
// fuses the final reduction into the same kernel via deterministic
// last-block-reduce (threadfence + ticket atomic; summation order fixed).

constexpr int D = 30;
constexpr int CPB = 128;                        // cells per block == threads
constexpr int BYTES_PER_TENSOR = CPB * D * 4;   // 15360 B per block per tensor
constexpr int LOADS_PER_WAVE = BYTES_PER_TENSOR / 1024;  // 15
constexpr float INV_S = 1.0f / 7.0f;

__global__ void __launch_bounds__(CPB) yolo_fused(
        const float* __restrict__ pred,
        const float* __restrict__ tgt,
        float* __restrict__ partial,
        unsigned int* __restrict__ counter,
        float* __restrict__ out,
        float inv_n) {
    __shared__ float lp[CPB * D];
    __shared__ float lt[CPB * D];

    const int lane = threadIdx.x & 63;
    const int wid  = threadIdx.x >> 6;

    // ---- async direct-to-LDS staging: wave 0 -> pred slab, wave 1 -> tgt ----
    {
        const char* gbase = (wid == 0)
            ? (const char*)pred + (size_t)blockIdx.x * BYTES_PER_TENSOR
            : (const char*)tgt  + (size_t)blockIdx.x * BYTES_PER_TENSOR;
        char* lbase = (wid == 0) ? (char*)lp : (char*)lt;
#pragma unroll
        for (int k = 0; k < LOADS_PER_WAVE; ++k) {
            __builtin_amdgcn_global_load_lds(
                (const __attribute__((address_space(1))) void*)
                    (gbase + k * 1024 + lane * 16),
                (__attribute__((address_space(3))) void*)(lbase + k * 1024),
                16, 0, 0);
        }
    }
    __syncthreads();   // drains vmcnt before any LDS read

    const float* p = &lp[threadIdx.x * D];
    const float* t = &lt[threadIdx.x * D];

    // ---- boxes (10 floats each tensor) via float2 LDS reads ----
    float pb[10], tb[10];
#pragma unroll
    for (int j = 0; j < 5; ++j) {
        float2 v = *reinterpret_cast<const float2*>(p + 2 * j);
        pb[2 * j] = v.x; pb[2 * j + 1] = v.y;
        float2 w = *reinterpret_cast<const float2*>(t + 2 * j);
        tb[2 * j] = w.x; tb[2 * j + 1] = w.y;
    }

    // ---- class loss (20 floats each) ----
    float lcls = 0.f;
#pragma unroll
    for (int j = 0; j < 10; ++j) {
        float2 pc = *reinterpret_cast<const float2*>(p + 10 + 2 * j);
        float2 tc = *reinterpret_cast<const float2*>(t + 10 + 2 * j);
        float dx = pc.x - tc.x;
        float dy = pc.y - tc.y;
        lcls += dx * dx + dy * dy;
    }

    float m_obj   = (tb[4] >  0.f) ? 1.f : 0.f;
    float m_noobj = (tb[4] == 0.f) ? 1.f : 0.f;

    // ---- target box 0 corners (xyxy) ----
    float t_x1 = tb[0] * INV_S - 0.5f * tb[2];
    float t_y1 = tb[1] * INV_S - 0.5f * tb[3];
    float t_x2 = tb[0] * INV_S + 0.5f * tb[2];
    float t_y2 = tb[1] * INV_S + 0.5f * tb[3];
    float area_t = (t_x2 - t_x1) * (t_y2 - t_y1);

    // ---- IoU of both pred boxes vs target box 0 ----
    float iou0, iou1;
#pragma unroll
    for (int b = 0; b < 2; ++b) {
        float x = pb[5 * b + 0], y = pb[5 * b + 1];
        float w = pb[5 * b + 2], h = pb[5 * b + 3];
        float p_x1 = x * INV_S - 0.5f * w;
        float p_y1 = y * INV_S - 0.5f * h;
        float p_x2 = x * INV_S + 0.5f * w;
        float p_y2 = y * INV_S + 0.5f * h;
        float lt_x = fmaxf(p_x1, t_x1), lt_y = fmaxf(p_y1, t_y1);
        float rb_x = fminf(p_x2, t_x2), rb_y = fminf(p_y2, t_y2);
        float iw = fmaxf(rb_x - lt_x, 0.f);
        float ih = fmaxf(rb_y - lt_y, 0.f);
        float inter = iw * ih;
        float area_p = (p_x2 - p_x1) * (p_y2 - p_y1);
        float uni = area_p + area_t - inter;
        float r = inter / (uni + 1e-10f);
        if (b == 0) iou0 = r; else iou1 = r;
    }

    // jnp.argmax picks the FIRST max -> box 1 wins only on strict >
    bool r1 = iou1 > iou0;
    float max_iou = fmaxf(iou0, iou1);

    float prx = r1 ? pb[5] : pb[0];
    float pry = r1 ? pb[6] : pb[1];
    float prw = r1 ? pb[7] : pb[2];
    float prh = r1 ? pb[8] : pb[3];
    float prc = r1 ? pb[9] : pb[4];
    float trx = r1 ? tb[5] : tb[0];
    float try_ = r1 ? tb[6] : tb[1];
    float trw = r1 ? tb[7] : tb[2];
    float trh = r1 ? tb[8] : tb[3];

    float dx = prx - trx, dy = pry - try_;
    float dxy = dx * dx + dy * dy;
    float sw = sqrtf(prw) - sqrtf(trw);
    float sh = sqrtf(prh) - sqrtf(trh);
    float dwh = sw * sw + sh * sh;
    float doj = prc - max_iou;
    float dobj = doj * doj;
    float dn0 = pb[4] - tb[4];
    float dn1 = pb[9] - tb[9];
    float dnoobj = dn0 * dn0 + dn1 * dn1;

    float loss = m_obj * (5.0f * (dxy + dwh) + dobj + lcls)
               + 0.5f * m_noobj * dnoobj;

    // ---- block reduction: wave shuffle then LDS across 2 waves ----
#pragma unroll
    for (int off = 32; off > 0; off >>= 1)
        loss += __shfl_down(loss, off, 64);
    __shared__ float wsum[2];
    if (lane == 0) wsum[wid] = loss;
    __syncthreads();

    // ---- deterministic last-block-reduce ----
    __shared__ bool amLast;
    if (threadIdx.x == 0) {
        partial[blockIdx.x] = wsum[0] + wsum[1];
        __threadfence();                       // release: partial visible device-wide
        unsigned int prev = atomicAdd(counter, 1u);
        amLast = (prev == gridDim.x - 1);
    }
    __syncthreads();

    if (amLast) {
        __threadfence();                       // acquire: see all partials
        float s = 0.f;
        for (unsigned int i = threadIdx.x; i < gridDim.x; i += CPB)
            s += partial[i];                   // fixed per-thread order
#pragma unroll
        for (int off = 32; off > 0; off >>= 1)
            s += __shfl_down(s, off, 64);
        if (lane == 0) wsum[wid] = s;
        __syncthreads();                       // block-local, only last block here
        if (threadIdx.x == 0)
            out[0] = (wsum[0] + wsum[1]) * inv_n;
    }
}

extern "C" void kernel_launch(void* const* d_in, const int* in_sizes, int n_in,
                              void* d_out, int out_size, void* d_ws, size_t ws_size,
                              hipStream_t stream) {
    const float* pred = (const float*)d_in[0];
    const float* tgt  = (const float*)d_in[1];
    float* out = (float*)d_out;

    unsigned int* counter = (unsigned int*)d_ws;          // 4 B ticket
    float* partial = (float*)((char*)d_ws + 256);         // 6272 floats

    int ncells  = in_sizes[0] / D;           // N * 7 * 7 = 802816
    int nblocks = ncells / CPB;              // 6272 (divides exactly)
    float inv_n = 49.0f / (float)ncells;     // 1 / N

    hipMemsetAsync(counter, 0, sizeof(unsigned int), stream);
    yolo_fused<<<nblocks, CPB, 0, stream>>>(pred, tgt, partial, counter, out, inv_n);
}

// Round 5
// 35.843 us; speedup vs baseline: 6.5676x; 6.5676x over previous
//
#include <hip/hip_runtime.h>

// YOLO v1 loss, forward only.
// predictions/target: (N, 7, 7, 30) f32, D = 2*5 + 20. Output: scalar f32.
//
// R4 post-mortem: last-block-reduce fusion regressed 6x — per-block
// device-scope __threadfence serialized/flushed the streaming pipeline.
// Reverted to two kernels. R5 shaves overhead: single-wave blocks (no
// cross-wave barrier coupling, each wave drains only its own DMA loads,
// partial written straight from the shuffle reduce), float4 stage2.
// Stage1 runs at ~5.9 TB/s effective = ~93% of the measured streaming
// ceiling; this round targets the residual sync/epilogue cost.

constexpr int D = 30;
constexpr int CPB = 64;                     // one wave per block
constexpr int SLAB = CPB * D * 4;           // 7680 B per tensor per block
constexpr float INV_S = 1.0f / 7.0f;

__global__ void __launch_bounds__(64) yolo_stage1(
        const float* __restrict__ pred,
        const float* __restrict__ tgt,
        float* __restrict__ partial) {
    __shared__ float lp[CPB * D];   // 7680 B
    __shared__ float lt[CPB * D];   // 7680 B

    const int lane = threadIdx.x;   // 0..63 (single wave)

    const char* pg = (const char*)pred + (size_t)blockIdx.x * SLAB;
    const char* tg = (const char*)tgt  + (size_t)blockIdx.x * SLAB;

    // ---- async direct-to-LDS staging: 7 full 1024B DMA ops + 512B tail ----
#pragma unroll
    for (int k = 0; k < 7; ++k) {
        __builtin_amdgcn_global_load_lds(
            (const __attribute__((address_space(1))) void*)(pg + k * 1024 + lane * 16),
            (__attribute__((address_space(3))) void*)((char*)lp + k * 1024),
            16, 0, 0);
        __builtin_amdgcn_global_load_lds(
            (const __attribute__((address_space(1))) void*)(tg + k * 1024 + lane * 16),
            (__attribute__((address_space(3))) void*)((char*)lt + k * 1024),
            16, 0, 0);
    }
    if (lane < 32) {   // tail: 512 B per tensor, lanes 0-31
        __builtin_amdgcn_global_load_lds(
            (const __attribute__((address_space(1))) void*)(pg + 7 * 1024 + lane * 16),
            (__attribute__((address_space(3))) void*)((char*)lp + 7 * 1024),
            16, 0, 0);
        __builtin_amdgcn_global_load_lds(
            (const __attribute__((address_space(1))) void*)(tg + 7 * 1024 + lane * 16),
            (__attribute__((address_space(3))) void*)((char*)lt + 7 * 1024),
            16, 0, 0);
    }
    __syncthreads();   // single wave: just the vmcnt/lgkmcnt drain + cheap barrier

    const float* p = &lp[lane * D];
    const float* t = &lt[lane * D];

    // ---- boxes (10 floats each tensor) via float2 LDS reads ----
    float pb[10], tb[10];
#pragma unroll
    for (int j = 0; j < 5; ++j) {
        float2 v = *reinterpret_cast<const float2*>(p + 2 * j);
        pb[2 * j] = v.x; pb[2 * j + 1] = v.y;
        float2 w = *reinterpret_cast<const float2*>(t + 2 * j);
        tb[2 * j] = w.x; tb[2 * j + 1] = w.y;
    }

    // ---- class loss (20 floats each) ----
    float lcls = 0.f;
#pragma unroll
    for (int j = 0; j < 10; ++j) {
        float2 pc = *reinterpret_cast<const float2*>(p + 10 + 2 * j);
        float2 tc = *reinterpret_cast<const float2*>(t + 10 + 2 * j);
        float dx = pc.x - tc.x;
        float dy = pc.y - tc.y;
        lcls += dx * dx + dy * dy;
    }

    float m_obj   = (tb[4] >  0.f) ? 1.f : 0.f;
    float m_noobj = (tb[4] == 0.f) ? 1.f : 0.f;

    // ---- target box 0 corners (xyxy) ----
    float t_x1 = tb[0] * INV_S - 0.5f * tb[2];
    float t_y1 = tb[1] * INV_S - 0.5f * tb[3];
    float t_x2 = tb[0] * INV_S + 0.5f * tb[2];
    float t_y2 = tb[1] * INV_S + 0.5f * tb[3];
    float area_t = (t_x2 - t_x1) * (t_y2 - t_y1);

    // ---- IoU of both pred boxes vs target box 0 ----
    float iou0, iou1;
#pragma unroll
    for (int b = 0; b < 2; ++b) {
        float x = pb[5 * b + 0], y = pb[5 * b + 1];
        float w = pb[5 * b + 2], h = pb[5 * b + 3];
        float p_x1 = x * INV_S - 0.5f * w;
        float p_y1 = y * INV_S - 0.5f * h;
        float p_x2 = x * INV_S + 0.5f * w;
        float p_y2 = y * INV_S + 0.5f * h;
        float lt_x = fmaxf(p_x1, t_x1), lt_y = fmaxf(p_y1, t_y1);
        float rb_x = fminf(p_x2, t_x2), rb_y = fminf(p_y2, t_y2);
        float iw = fmaxf(rb_x - lt_x, 0.f);
        float ih = fmaxf(rb_y - lt_y, 0.f);
        float inter = iw * ih;
        float area_p = (p_x2 - p_x1) * (p_y2 - p_y1);
        float uni = area_p + area_t - inter;
        float r = inter / (uni + 1e-10f);
        if (b == 0) iou0 = r; else iou1 = r;
    }

    // jnp.argmax picks the FIRST max -> box 1 wins only on strict >
    bool r1 = iou1 > iou0;
    float max_iou = fmaxf(iou0, iou1);

    float prx = r1 ? pb[5] : pb[0];
    float pry = r1 ? pb[6] : pb[1];
    float prw = r1 ? pb[7] : pb[2];
    float prh = r1 ? pb[8] : pb[3];
    float prc = r1 ? pb[9] : pb[4];
    float trx = r1 ? tb[5] : tb[0];
    float try_ = r1 ? tb[6] : tb[1];
    float trw = r1 ? tb[7] : tb[2];
    float trh = r1 ? tb[8] : tb[3];

    float dx = prx - trx, dy = pry - try_;
    float dxy = dx * dx + dy * dy;
    float sw = sqrtf(prw) - sqrtf(trw);
    float sh = sqrtf(prh) - sqrtf(trh);
    float dwh = sw * sw + sh * sh;
    float doj = prc - max_iou;
    float dobj = doj * doj;
    float dn0 = pb[4] - tb[4];
    float dn1 = pb[9] - tb[9];
    float dnoobj = dn0 * dn0 + dn1 * dn1;

    float loss = m_obj * (5.0f * (dxy + dwh) + dobj + lcls)
               + 0.5f * m_noobj * dnoobj;

    // ---- wave shuffle reduction, lane 0 stores the block partial ----
#pragma unroll
    for (int off = 32; off > 0; off >>= 1)
        loss += __shfl_down(loss, off, 64);
    if (lane == 0)
        partial[blockIdx.x] = loss;
}

__global__ void __launch_bounds__(1024) yolo_stage2(
        const float* __restrict__ partial, int n4,
        float* __restrict__ out, float inv_n) {
    const float4* __restrict__ p4 = reinterpret_cast<const float4*>(partial);
    float s = 0.f;
    for (int i = threadIdx.x; i < n4; i += 1024) {
        float4 v = p4[i];
        s += ((v.x + v.y) + (v.z + v.w));
    }
#pragma unroll
    for (int off = 32; off > 0; off >>= 1)
        s += __shfl_down(s, off, 64);
    __shared__ float w[16];
    int lane = threadIdx.x & 63;
    int wid  = threadIdx.x >> 6;
    if (lane == 0) w[wid] = s;
    __syncthreads();
    if (threadIdx.x == 0) {
        float tot = 0.f;
#pragma unroll
        for (int i = 0; i < 16; ++i) tot += w[i];
        out[0] = tot * inv_n;
    }
}

extern "C" void kernel_launch(void* const* d_in, const int* in_sizes, int n_in,
                              void* d_out, int out_size, void* d_ws, size_t ws_size,
                              hipStream_t stream) {
    const float* pred = (const float*)d_in[0];
    const float* tgt  = (const float*)d_in[1];
    float* out     = (float*)d_out;
    float* partial = (float*)d_ws;

    int ncells  = in_sizes[0] / D;           // N * 7 * 7 = 802816
    int nblocks = ncells / CPB;              // 12544 (divides exactly)
    float inv_n = 49.0f / (float)ncells;     // 1 / N

    yolo_stage1<<<nblocks, CPB, 0, stream>>>(pred, tgt, partial);
    yolo_stage2<<<1, 1024, 0, stream>>>(partial, nblocks / 4, out, inv_n);
}